// Round 1
// baseline (586.246 us; speedup 1.0000x reference)
//
#include <hip/hip_runtime.h>
#include <hip/hip_bf16.h>
#include <stdint.h>

#define SEQL 2048
#define EMB 4096
#define KVDIM 1024
#define NHEADS 32
#define HD 128

typedef __attribute__((ext_vector_type(4))) float f32x4;
typedef __attribute__((ext_vector_type(8))) short bf16x8;
typedef unsigned short u16;
typedef unsigned int u32;

__device__ __forceinline__ u16 f2bf(float f) {
  u32 u = __builtin_bit_cast(u32, f);
  u = (u + 0x7FFFu + ((u >> 16) & 1u)) >> 16;
  return (u16)u;
}

__device__ __forceinline__ void gload_lds16(const void* g, void* l) {
  __builtin_amdgcn_global_load_lds(
      (const __attribute__((address_space(1))) void*)g,
      (__attribute__((address_space(3))) void*)l, 16, 0, 0);
}

// ---------------- fp32 -> bf16 conversion (x + 4 weight matrices) ------------
__global__ __launch_bounds__(256) void k_convert(
    const float* __restrict__ x, const float* __restrict__ qw,
    const float* __restrict__ kw, const float* __restrict__ vw,
    const float* __restrict__ ow, u16* __restrict__ xb, u16* __restrict__ qwb,
    u16* __restrict__ kwb, u16* __restrict__ vwb, u16* __restrict__ owb) {
  const long NCH = 6291456;  // 50331648 / 8
  const long stride = (long)gridDim.x * 256;
  for (long c = (long)blockIdx.x * 256 + threadIdx.x; c < NCH; c += stride) {
    long i = c << 3;
    const float* s;
    u16* d;
    long off;
    if (i < 8388608) {
      s = x; d = xb; off = i;
    } else if (i < 25165824) {
      s = qw; d = qwb; off = i - 8388608;
    } else if (i < 29360128) {
      s = kw; d = kwb; off = i - 25165824;
    } else if (i < 33554432) {
      s = vw; d = vwb; off = i - 29360128;
    } else {
      s = ow; d = owb; off = i - 33554432;
    }
    float4 a = *(const float4*)(s + off);
    float4 b = *(const float4*)(s + off + 4);
    bf16x8 o;
    o[0] = f2bf(a.x); o[1] = f2bf(a.y); o[2] = f2bf(a.z); o[3] = f2bf(a.w);
    o[4] = f2bf(b.x); o[5] = f2bf(b.y); o[6] = f2bf(b.z); o[7] = f2bf(b.w);
    *(bf16x8*)(d + off) = o;
  }
}

// ---------------- 128x128-tile bf16 GEMM core (C = A * W^T), m97 structure ---
__device__ __forceinline__ void gemm_core128(const u16* __restrict__ A,
                                             const u16* __restrict__ W, long m0,
                                             long n0, int lda, int ldb, int nkt,
                                             u16* sA, u16* sB, f32x4 acc[4][4]) {
  const int t = threadIdx.x, lane = t & 63, w = t >> 6;
  const int wr = w >> 1, wc = w & 1, r15 = lane & 15, kof = (lane >> 4) * 8;
  auto stage = [&](int buf, int kt) {
    const long k0 = (long)kt * 32;
#pragma unroll
    for (int i = 0; i < 2; ++i) {
      const int L = (i * 256 + t) * 8;
      gload_lds16(A + (m0 + (L >> 5)) * lda + k0 + (L & 31),
                  sA + buf * 4096 + i * 2048 + w * 512);
      gload_lds16(W + (n0 + (L >> 5)) * ldb + k0 + (L & 31),
                  sB + buf * 4096 + i * 2048 + w * 512);
    }
  };
  stage(0, 0);
  __syncthreads();
  int cur = 0;
  for (int kt = 0; kt < nkt; ++kt) {
    if (kt + 1 < nkt) stage(cur ^ 1, kt + 1);
    bf16x8 aF[4], bF[4];
#pragma unroll
    for (int m = 0; m < 4; ++m)
      aF[m] = *(const bf16x8*)(sA + cur * 4096 + (wr * 64 + m * 16 + r15) * 32 + kof);
#pragma unroll
    for (int n = 0; n < 4; ++n)
      bF[n] = *(const bf16x8*)(sB + cur * 4096 + (wc * 64 + n * 16 + r15) * 32 + kof);
#pragma unroll
    for (int m = 0; m < 4; ++m)
#pragma unroll
      for (int n = 0; n < 4; ++n)
        acc[m][n] =
            __builtin_amdgcn_mfma_f32_16x16x32_bf16(aF[m], bF[n], acc[m][n], 0, 0, 0);
    __syncthreads();
    cur ^= 1;
  }
}

// ---------------- fused QKV projection -------------------------------------
__global__ __launch_bounds__(256, 2) void k_gemm_qkv(
    const u16* __restrict__ xb, const u16* __restrict__ qwb,
    const u16* __restrict__ kwb, const u16* __restrict__ vwb,
    const float* __restrict__ qb, const float* __restrict__ kb,
    const float* __restrict__ vb, u16* __restrict__ Q, u16* __restrict__ Kc,
    u16* __restrict__ Vt) {
  __shared__ u16 sA[2 * 4096];
  __shared__ u16 sB[2 * 4096];
  const int nt = blockIdx.x, mt = blockIdx.y;
  const u16* W;
  const float* bias;
  long n0;
  int mode;
  if (nt < 32) {
    W = qwb; bias = qb; n0 = (long)nt * 128; mode = 0;
  } else if (nt < 40) {
    W = kwb; bias = kb; n0 = (long)(nt - 32) * 128; mode = 1;
  } else {
    W = vwb; bias = vb; n0 = (long)(nt - 40) * 128; mode = 2;
  }
  const long m0 = (long)mt * 128;
  f32x4 acc[4][4] = {};
  gemm_core128(xb, W, m0, n0, EMB, EMB, 128, sA, sB, acc);
  const int lane = threadIdx.x & 63, w = threadIdx.x >> 6;
  const int wr = w >> 1, wc = w & 1, r15 = lane & 15, hi = lane >> 4;
#pragma unroll
  for (int n = 0; n < 4; ++n) {
    const long col = n0 + wc * 64 + n * 16 + r15;
    const float bv = bias[col];
#pragma unroll
    for (int m = 0; m < 4; ++m) {
#pragma unroll
      for (int i = 0; i < 4; ++i) {
        const long row = m0 + wr * 64 + m * 16 + hi * 4 + i;
        const float v = acc[m][n][i] + bv;
        if (mode == 0)
          Q[row * EMB + col] = f2bf(v);
        else if (mode == 1)
          Kc[row * KVDIM + col] = f2bf(v);
        else
          Vt[col * SEQL + row] = f2bf(v);  // write V transposed: [kv_feat][s]
      }
    }
  }
}

// ---------------- flash attention with base-2 softermax ---------------------
__global__ __launch_bounds__(256, 2) void k_attn(const u16* __restrict__ Q,
                                                 const u16* __restrict__ Kc,
                                                 const u16* __restrict__ Vt,
                                                 u16* __restrict__ AO) {
  __shared__ u16 sK[64 * 128];   // [key][d], XOR-swizzled rows
  __shared__ u16 sV[128 * 64];   // [d][key], XOR-swizzled rows
  __shared__ u16 sP[4][32 * 72]; // per-wave P, padded +8
  const int h = blockIdx.y, kvh = h >> 2;
  const long q0 = (long)blockIdx.x * 128;
  const int t = threadIdx.x, lane = t & 63, w = t >> 6;
  const int r15 = lane & 15, hi = lane >> 4, kof = hi * 8;
  const float scale = 0.08838834764831845f;  // 1/sqrt(128)

  bf16x8 qf[2][4];
#pragma unroll
  for (int m = 0; m < 2; ++m)
#pragma unroll
    for (int ks = 0; ks < 4; ++ks)
      qf[m][ks] = *(const bf16x8*)(Q + (q0 + w * 32 + m * 16 + r15) * EMB +
                                   h * HD + ks * 32 + kof);

  f32x4 oacc[2][8] = {};
  float mx[2][4], sm[2][4];
#pragma unroll
  for (int m = 0; m < 2; ++m)
#pragma unroll
    for (int i = 0; i < 4; ++i) {
      mx[m][i] = -1e30f;
      sm[m][i] = 0.f;
    }

  for (int tk = 0; tk < 32; ++tk) {
    const long k0 = (long)tk * 64;
    __syncthreads();  // prior tile's LDS reads complete
#pragma unroll
    for (int i = 0; i < 4; ++i) {
      const int P = (i * 256 + t) * 16;
      // K tile: rows 256B; inverse-swizzled source so swizzled reads are linear
      const int row = P >> 8;
      const int cb = (P & 255) ^ ((row & 7) << 4);
      gload_lds16(Kc + (k0 + row) * KVDIM + kvh * HD + (cb >> 1),
                  (char*)sK + (i * 256 + w * 64) * 16);
      // V tile: rows 128B
      const int rowv = P >> 7;
      const int cbv = (P & 127) ^ ((rowv & 7) << 4);
      gload_lds16(Vt + (long)(kvh * HD + rowv) * SEQL + k0 + (cbv >> 1),
                  (char*)sV + (i * 256 + w * 64) * 16);
    }
    __syncthreads();  // staging complete
    // S = Q K^T  (raw dot; scale folded into softmax)
    f32x4 sacc[2][4] = {};
#pragma unroll
    for (int ks = 0; ks < 4; ++ks) {
      bf16x8 bF[4];
#pragma unroll
      for (int n = 0; n < 4; ++n) {
        const int row = n * 16 + r15;
        const int off = (row << 8) + (((ks * 32 + kof) << 1) ^ ((row & 7) << 4));
        bF[n] = *(const bf16x8*)((const char*)sK + off);
      }
#pragma unroll
      for (int m = 0; m < 2; ++m)
#pragma unroll
        for (int n = 0; n < 4; ++n)
          sacc[m][n] = __builtin_amdgcn_mfma_f32_16x16x32_bf16(qf[m][ks], bF[n],
                                                               sacc[m][n], 0, 0, 0);
    }
    // online base-2 softmax
#pragma unroll
    for (int m = 0; m < 2; ++m) {
#pragma unroll
      for (int i = 0; i < 4; ++i) {
        float tmax = fmaxf(fmaxf(sacc[m][0][i], sacc[m][1][i]),
                           fmaxf(sacc[m][2][i], sacc[m][3][i]));
#pragma unroll
        for (int msk = 1; msk < 16; msk <<= 1)
          tmax = fmaxf(tmax, __shfl_xor(tmax, msk, 64));
        const float nm = fmaxf(mx[m][i], tmax * scale);
        const float corr = exp2f(mx[m][i] - nm);
        mx[m][i] = nm;
        sm[m][i] *= corr;
#pragma unroll
        for (int n = 0; n < 8; ++n) oacc[m][n][i] *= corr;
        float ps = 0.f;
#pragma unroll
        for (int n = 0; n < 4; ++n) {
          const float p = exp2f(sacc[m][n][i] * scale - nm);
          ps += p;
          sP[w][(m * 16 + hi * 4 + i) * 72 + n * 16 + r15] = f2bf(p);
        }
#pragma unroll
        for (int msk = 1; msk < 16; msk <<= 1) ps += __shfl_xor(ps, msk, 64);
        sm[m][i] += ps;
      }
    }
    // O += P V
#pragma unroll
    for (int ks = 0; ks < 2; ++ks) {
      bf16x8 pF[2];
#pragma unroll
      for (int m = 0; m < 2; ++m)
        pF[m] = *(const bf16x8*)(&sP[w][(m * 16 + r15) * 72 + ks * 32 + kof]);
#pragma unroll
      for (int n = 0; n < 8; ++n) {
        const int row = n * 16 + r15;
        const int off = (row << 7) + (((ks * 32 + kof) << 1) ^ ((row & 7) << 4));
        const bf16x8 vF = *(const bf16x8*)((const char*)sV + off);
#pragma unroll
        for (int m = 0; m < 2; ++m)
          oacc[m][n] =
              __builtin_amdgcn_mfma_f32_16x16x32_bf16(pF[m], vF, oacc[m][n], 0, 0, 0);
      }
    }
  }
  // normalize + store
#pragma unroll
  for (int m = 0; m < 2; ++m) {
    float inv[4];
#pragma unroll
    for (int i = 0; i < 4; ++i) inv[i] = 1.f / sm[m][i];
#pragma unroll
    for (int n = 0; n < 8; ++n)
#pragma unroll
      for (int i = 0; i < 4; ++i)
        AO[(q0 + w * 32 + m * 16 + hi * 4 + i) * EMB + h * HD + n * 16 + r15] =
            f2bf(oacc[m][n][i] * inv[i]);
  }
}

// ---------------- output projection (fp32 out) ------------------------------
__global__ __launch_bounds__(256, 2) void k_gemm_o(const u16* __restrict__ AO,
                                                   const u16* __restrict__ owb,
                                                   const float* __restrict__ ob,
                                                   float* __restrict__ OUT) {
  __shared__ u16 sA[2 * 4096];
  __shared__ u16 sB[2 * 4096];
  const long n0 = (long)blockIdx.x * 128, m0 = (long)blockIdx.y * 128;
  f32x4 acc[4][4] = {};
  gemm_core128(AO, owb, m0, n0, EMB, EMB, 128, sA, sB, acc);
  const int lane = threadIdx.x & 63, w = threadIdx.x >> 6;
  const int wr = w >> 1, wc = w & 1, r15 = lane & 15, hi = lane >> 4;
#pragma unroll
  for (int n = 0; n < 4; ++n) {
    const long col = n0 + wc * 64 + n * 16 + r15;
    const float bv = ob[col];
#pragma unroll
    for (int m = 0; m < 4; ++m) {
#pragma unroll
      for (int i = 0; i < 4; ++i) {
        const long row = m0 + wr * 64 + m * 16 + hi * 4 + i;
        OUT[row * EMB + col] = acc[m][n][i] + bv;
      }
    }
  }
}

extern "C" void kernel_launch(void* const* d_in, const int* in_sizes, int n_in,
                              void* d_out, int out_size, void* d_ws,
                              size_t ws_size, hipStream_t stream) {
  const float* x = (const float*)d_in[0];
  const float* qw = (const float*)d_in[1];
  const float* qb = (const float*)d_in[2];
  const float* kw = (const float*)d_in[3];
  const float* kb = (const float*)d_in[4];
  const float* vw = (const float*)d_in[5];
  const float* vb = (const float*)d_in[6];
  const float* ow = (const float*)d_in[7];
  const float* ob = (const float*)d_in[8];
  float* OUT = (float*)d_out;

  char* ws = (char*)d_ws;
  u16* xb = (u16*)ws;   ws += 16777216;
  u16* qwb = (u16*)ws;  ws += 33554432;
  u16* kwb = (u16*)ws;  ws += 8388608;
  u16* vwb = (u16*)ws;  ws += 8388608;
  u16* owb = (u16*)ws;  ws += 33554432;
  u16* Qb = (u16*)ws;   ws += 16777216;
  u16* Kb = (u16*)ws;   ws += 4194304;
  u16* Vtb = (u16*)ws;  ws += 4194304;
  u16* AO = (u16*)ws;   ws += 16777216;

  k_convert<<<2048, 256, 0, stream>>>(x, qw, kw, vw, ow, xb, qwb, kwb, vwb, owb);
  k_gemm_qkv<<<dim3(48, 16), 256, 0, stream>>>(xb, qwb, kwb, vwb, qb, kb, vb,
                                               Qb, Kb, Vtb);
  k_attn<<<dim3(16, 32), 256, 0, stream>>>(Qb, Kb, Vtb, AO);
  k_gemm_o<<<dim3(32, 16), 256, 0, stream>>>(AO, owb, ob, OUT);
}

// Round 2
// 575.024 us; speedup vs baseline: 1.0195x; 1.0195x over previous
//
#include <hip/hip_runtime.h>
#include <hip/hip_bf16.h>
#include <stdint.h>

#define SEQL 2048
#define EMB 4096
#define KVDIM 1024
#define HD 128

typedef __attribute__((ext_vector_type(4))) float f32x4;
typedef __attribute__((ext_vector_type(8))) short bf16x8;
typedef unsigned short u16;
typedef unsigned int u32;

__device__ __forceinline__ u16 f2bf(float f) {
  u32 u = __builtin_bit_cast(u32, f);
  u = (u + 0x7FFFu + ((u >> 16) & 1u)) >> 16;
  return (u16)u;
}

__device__ __forceinline__ void gload_lds16(const void* g, void* l) {
  __builtin_amdgcn_global_load_lds(
      (const __attribute__((address_space(1))) void*)g,
      (__attribute__((address_space(3))) void*)l, 16, 0, 0);
}

// ---------------- fp32 -> bf16 conversion (x + 4 weight matrices) ------------
__global__ __launch_bounds__(256) void k_convert(
    const float* __restrict__ x, const float* __restrict__ qw,
    const float* __restrict__ kw, const float* __restrict__ vw,
    const float* __restrict__ ow, u16* __restrict__ xb, u16* __restrict__ qwb,
    u16* __restrict__ kwb, u16* __restrict__ vwb, u16* __restrict__ owb) {
  const long NCH = 6291456;  // 50331648 / 8
  const long stride = (long)gridDim.x * 256;
  for (long c = (long)blockIdx.x * 256 + threadIdx.x; c < NCH; c += stride) {
    long i = c << 3;
    const float* s;
    u16* d;
    long off;
    if (i < 8388608) {
      s = x; d = xb; off = i;
    } else if (i < 25165824) {
      s = qw; d = qwb; off = i - 8388608;
    } else if (i < 29360128) {
      s = kw; d = kwb; off = i - 25165824;
    } else if (i < 33554432) {
      s = vw; d = vwb; off = i - 29360128;
    } else {
      s = ow; d = owb; off = i - 33554432;
    }
    float4 a = *(const float4*)(s + off);
    float4 b = *(const float4*)(s + off + 4);
    bf16x8 o;
    o[0] = f2bf(a.x); o[1] = f2bf(a.y); o[2] = f2bf(a.z); o[3] = f2bf(a.w);
    o[4] = f2bf(b.x); o[5] = f2bf(b.y); o[6] = f2bf(b.z); o[7] = f2bf(b.w);
    *(bf16x8*)(d + off) = o;
  }
}

// ---- GEMM core: 128x256 tile, BK=64, 8 waves, dbuf LDS, counted vmcnt ------
// C[aRow0..+128][bRow0..+256] = A(rows,K) * B(rows,K)^T ; lda/ldb in elements.
// LDS: per buf 49152B: A tile 128x64 (16KB, swizzled) + B tile 256x64 (32KB).
__device__ __forceinline__ void gemm_128x256(const u16* __restrict__ A,
                                             const u16* __restrict__ B,
                                             long aRow0, long bRow0, int lda,
                                             int ldb, u16* sm, f32x4 acc[4][4]) {
  const int t = threadIdx.x;
  const int lane = t & 63, w = t >> 6;
  const int wr = w >> 2, wc = w & 3;  // wave grid 2(M) x 4(N)
  const int r15 = lane & 15, hi = lane >> 4;
  const int rsub = lane >> 3;                  // row-within-chunk 0..7
  const int gofs = ((lane & 7) ^ rsub) << 3;   // pre-swizzled source granule
  const int swz0 = ((0 + hi) ^ (r15 & 7)) << 4;  // ks=0 granule -> byte
  const int swz1 = ((4 + hi) ^ (r15 & 7)) << 4;  // ks=1

  auto stage = [&](int buf, int kt) {
    const long k0 = (long)kt * 64 + gofs;
    u16* base = sm + buf * 24576;
#pragma unroll
    for (int i = 0; i < 2; ++i) {  // A: 128 rows = 16 chunks of 8 rows
      const int ch = i * 8 + w;
      gload_lds16(A + (aRow0 + ch * 8 + rsub) * (long)lda + k0, base + ch * 512);
    }
#pragma unroll
    for (int i = 0; i < 4; ++i) {  // B: 256 rows = 32 chunks
      const int ch = i * 8 + w;
      gload_lds16(B + (bRow0 + ch * 8 + rsub) * (long)ldb + k0,
                  base + 8192 + ch * 512);
    }
  };

  stage(0, 0);
  stage(1, 1);
  asm volatile("s_waitcnt vmcnt(6)" ::: "memory");
  __builtin_amdgcn_s_barrier();

  const char* sc = (const char*)sm;
  int cur = 0;
  for (int kt = 0; kt < 64; ++kt) {
    const char* base = sc + cur * 49152;
    const char* aB = base + (wr * 64 + r15) * 128;
    const char* bB = base + 16384 + (wc * 64 + r15) * 128;
    bf16x8 aF[4][2], bF[2][2];
#pragma unroll
    for (int m = 0; m < 4; ++m) {
      aF[m][0] = *(const bf16x8*)(aB + m * 2048 + swz0);
      aF[m][1] = *(const bf16x8*)(aB + m * 2048 + swz1);
    }
#pragma unroll
    for (int n = 0; n < 2; ++n) {
      bF[n][0] = *(const bf16x8*)(bB + n * 2048 + swz0);
      bF[n][1] = *(const bf16x8*)(bB + n * 2048 + swz1);
    }
    __builtin_amdgcn_s_setprio(1);
#pragma unroll
    for (int m = 0; m < 4; ++m)
#pragma unroll
      for (int n = 0; n < 2; ++n) {
        acc[m][n] = __builtin_amdgcn_mfma_f32_16x16x32_bf16(aF[m][0], bF[n][0],
                                                            acc[m][n], 0, 0, 0);
        acc[m][n] = __builtin_amdgcn_mfma_f32_16x16x32_bf16(aF[m][1], bF[n][1],
                                                            acc[m][n], 0, 0, 0);
      }
    __builtin_amdgcn_s_setprio(0);
    bf16x8 cF[2][2];
#pragma unroll
    for (int n = 0; n < 2; ++n) {
      cF[n][0] = *(const bf16x8*)(bB + (n + 2) * 2048 + swz0);
      cF[n][1] = *(const bf16x8*)(bB + (n + 2) * 2048 + swz1);
    }
    __builtin_amdgcn_s_setprio(1);
#pragma unroll
    for (int m = 0; m < 4; ++m)
#pragma unroll
      for (int n = 0; n < 2; ++n) {
        acc[m][n + 2] = __builtin_amdgcn_mfma_f32_16x16x32_bf16(
            aF[m][0], cF[n][0], acc[m][n + 2], 0, 0, 0);
        acc[m][n + 2] = __builtin_amdgcn_mfma_f32_16x16x32_bf16(
            aF[m][1], cF[n][1], acc[m][n + 2], 0, 0, 0);
      }
    __builtin_amdgcn_s_setprio(0);
    __builtin_amdgcn_s_barrier();  // all waves done reading buf `cur`
    if (kt + 2 < 64) {
      stage(cur, kt + 2);  // overwrite freed buffer
      asm volatile("s_waitcnt vmcnt(6)" ::: "memory");  // kt+1's 6 loads landed
    } else {
      asm volatile("s_waitcnt vmcnt(0)" ::: "memory");
    }
    __builtin_amdgcn_s_barrier();  // buf cur^1 ready for everyone
    cur ^= 1;
  }
}

// ---------------- fused QKV projection -------------------------------------
__global__ __launch_bounds__(512, 2) void k_gemm_qkv(
    const u16* __restrict__ xb, const u16* __restrict__ qwb,
    const u16* __restrict__ kwb, const u16* __restrict__ vwb,
    const float* __restrict__ qb, const float* __restrict__ kb,
    const float* __restrict__ vb, u16* __restrict__ Q, u16* __restrict__ Kc,
    u16* __restrict__ Vt) {
  __shared__ u16 sm[49152];
  const int nt = blockIdx.x, mt = blockIdx.y;
  const u16* W;
  const float* bias;
  long n0;
  int mode;
  if (nt < 16) {
    W = qwb; bias = qb; n0 = (long)nt * 256; mode = 0;
  } else if (nt < 20) {
    W = kwb; bias = kb; n0 = (long)(nt - 16) * 256; mode = 1;
  } else {
    W = vwb; bias = vb; n0 = (long)(nt - 20) * 256; mode = 2;
  }
  const long m0 = (long)mt * 128;
  f32x4 acc[4][4] = {};
  gemm_128x256(xb, W, m0, n0, EMB, EMB, sm, acc);
  const int lane = threadIdx.x & 63, w = threadIdx.x >> 6;
  const int wr = w >> 2, wc = w & 3, r15 = lane & 15, hi = lane >> 4;
#pragma unroll
  for (int n = 0; n < 4; ++n) {
    const long col = n0 + wc * 64 + n * 16 + r15;
    const float bv = bias[col];
#pragma unroll
    for (int m = 0; m < 4; ++m) {
#pragma unroll
      for (int j = 0; j < 4; ++j) {
        const long row = m0 + wr * 64 + m * 16 + hi * 4 + j;
        const float v = acc[m][n][j] + bv;
        if (mode == 0)
          Q[row * EMB + col] = f2bf(v);
        else if (mode == 1)
          Kc[row * KVDIM + col] = f2bf(v);
        else
          Vt[col * SEQL + row] = f2bf(v);  // V stored transposed [kv_feat][s]
      }
    }
  }
}

// ---------------- flash attention, base-2 softermax, 64-row q-tiles ---------
__global__ __launch_bounds__(256, 3) void k_attn(const u16* __restrict__ Q,
                                                 const u16* __restrict__ Kc,
                                                 const u16* __restrict__ Vt,
                                                 u16* __restrict__ AO) {
  __shared__ u16 sK[64 * 128];   // [key][d], XOR-swizzled 16B granules
  __shared__ u16 sV[128 * 64];   // [d][key], XOR-swizzled
  __shared__ u16 sP[4][16 * 72]; // per-wave P, pad +8
  const int h = blockIdx.y, kvh = h >> 2;
  const long q0 = (long)blockIdx.x * 64;
  const int t = threadIdx.x, lane = t & 63, w = t >> 6;
  const int r15 = lane & 15, hi = lane >> 4, kof = hi * 8;
  const float scale = 0.08838834764831845f;  // 1/sqrt(128)

  bf16x8 qf[4];
#pragma unroll
  for (int ks = 0; ks < 4; ++ks)
    qf[ks] = *(const bf16x8*)(Q + (q0 + w * 16 + r15) * EMB + h * HD + ks * 32 + kof);

  f32x4 oacc[8] = {};
  float mx[4], sms[4];
#pragma unroll
  for (int i = 0; i < 4; ++i) {
    mx[i] = -1e30f;
    sms[i] = 0.f;
  }

  for (int tk = 0; tk < 32; ++tk) {
    const long k0 = (long)tk * 64;
    __syncthreads();  // prior tile's LDS reads complete
#pragma unroll
    for (int i = 0; i < 4; ++i) {
      const int P = (i * 256 + t) * 16;
      const int row = P >> 8;
      const int cb = (P & 255) ^ ((row & 7) << 4);
      gload_lds16(Kc + (k0 + row) * KVDIM + kvh * HD + (cb >> 1),
                  (char*)sK + (i * 256 + w * 64) * 16);
      const int rowv = P >> 7;
      const int cbv = (P & 127) ^ ((rowv & 7) << 4);
      gload_lds16(Vt + (long)(kvh * HD + rowv) * SEQL + k0 + (cbv >> 1),
                  (char*)sV + (i * 256 + w * 64) * 16);
    }
    __syncthreads();  // staging complete
    // S = Q K^T
    f32x4 sacc[4] = {};
#pragma unroll
    for (int ks = 0; ks < 4; ++ks) {
      bf16x8 bF[4];
#pragma unroll
      for (int n = 0; n < 4; ++n) {
        const int row = n * 16 + r15;
        const int off = (row << 8) + (((ks * 32 + kof) << 1) ^ ((row & 7) << 4));
        bF[n] = *(const bf16x8*)((const char*)sK + off);
      }
#pragma unroll
      for (int n = 0; n < 4; ++n)
        sacc[n] = __builtin_amdgcn_mfma_f32_16x16x32_bf16(qf[ks], bF[n], sacc[n],
                                                          0, 0, 0);
    }
    // online base-2 softmax with defer-max (T13) + per-lane partial sums
#pragma unroll
    for (int i = 0; i < 4; ++i) {
      const float pm = fmaxf(fmaxf(sacc[0][i], sacc[1][i]),
                             fmaxf(sacc[2][i], sacc[3][i]));
      if (__any(pm * scale > mx[i] + 8.0f)) {
        float tmax = pm;
#pragma unroll
        for (int msk = 1; msk < 16; msk <<= 1)
          tmax = fmaxf(tmax, __shfl_xor(tmax, msk, 64));
        const float nm = fmaxf(mx[i], tmax * scale);
        const float corr = exp2f(mx[i] - nm);
        mx[i] = nm;
        sms[i] *= corr;
#pragma unroll
        for (int n = 0; n < 8; ++n) oacc[n][i] *= corr;
      }
      float ps = 0.f;
#pragma unroll
      for (int n = 0; n < 4; ++n) {
        const float p = exp2f(sacc[n][i] * scale - mx[i]);
        ps += p;
        sP[w][(hi * 4 + i) * 72 + n * 16 + r15] = f2bf(p);
      }
      sms[i] += ps;  // per-lane partial; reduced once at the end
    }
    // O += P V
#pragma unroll
    for (int ks = 0; ks < 2; ++ks) {
      const bf16x8 pF = *(const bf16x8*)(&sP[w][r15 * 72 + ks * 32 + kof]);
#pragma unroll
      for (int n = 0; n < 8; ++n) {
        const int row = n * 16 + r15;
        const int off = (row << 7) + (((ks * 32 + kof) << 1) ^ ((row & 7) << 4));
        const bf16x8 vF = *(const bf16x8*)((const char*)sV + off);
        oacc[n] = __builtin_amdgcn_mfma_f32_16x16x32_bf16(pF, vF, oacc[n], 0, 0, 0);
      }
    }
  }
  // final row-sum reduce + normalize + store
  float inv[4];
#pragma unroll
  for (int i = 0; i < 4; ++i) {
    float s = sms[i];
#pragma unroll
    for (int msk = 1; msk < 16; msk <<= 1) s += __shfl_xor(s, msk, 64);
    inv[i] = 1.f / s;
  }
#pragma unroll
  for (int n = 0; n < 8; ++n)
#pragma unroll
    for (int i = 0; i < 4; ++i)
      AO[(q0 + w * 16 + hi * 4 + i) * EMB + h * HD + n * 16 + r15] =
          f2bf(oacc[n][i] * inv[i]);
}

// ---------------- output projection (fp32 out) ------------------------------
__global__ __launch_bounds__(512, 2) void k_gemm_o(const u16* __restrict__ AO,
                                                   const u16* __restrict__ owb,
                                                   const float* __restrict__ ob,
                                                   float* __restrict__ OUT) {
  __shared__ u16 sm[49152];
  const long n0 = (long)blockIdx.x * 256, m0 = (long)blockIdx.y * 128;
  f32x4 acc[4][4] = {};
  gemm_128x256(AO, owb, m0, n0, EMB, EMB, sm, acc);
  const int lane = threadIdx.x & 63, w = threadIdx.x >> 6;
  const int wr = w >> 2, wc = w & 3, r15 = lane & 15, hi = lane >> 4;
#pragma unroll
  for (int n = 0; n < 4; ++n) {
    const long col = n0 + wc * 64 + n * 16 + r15;
    const float bv = ob[col];
#pragma unroll
    for (int m = 0; m < 4; ++m) {
#pragma unroll
      for (int j = 0; j < 4; ++j) {
        const long row = m0 + wr * 64 + m * 16 + hi * 4 + j;
        OUT[row * EMB + col] = acc[m][n][j] + bv;
      }
    }
  }
}

extern "C" void kernel_launch(void* const* d_in, const int* in_sizes, int n_in,
                              void* d_out, int out_size, void* d_ws,
                              size_t ws_size, hipStream_t stream) {
  const float* x = (const float*)d_in[0];
  const float* qw = (const float*)d_in[1];
  const float* qb = (const float*)d_in[2];
  const float* kw = (const float*)d_in[3];
  const float* kb = (const float*)d_in[4];
  const float* vw = (const float*)d_in[5];
  const float* vb = (const float*)d_in[6];
  const float* ow = (const float*)d_in[7];
  const float* ob = (const float*)d_in[8];
  float* OUT = (float*)d_out;

  char* ws = (char*)d_ws;
  u16* xb = (u16*)ws;   ws += 16777216;
  u16* qwb = (u16*)ws;  ws += 33554432;
  u16* kwb = (u16*)ws;  ws += 8388608;
  u16* vwb = (u16*)ws;  ws += 8388608;
  u16* owb = (u16*)ws;  ws += 33554432;
  u16* Qb = (u16*)ws;   ws += 16777216;
  u16* Kb = (u16*)ws;   ws += 4194304;
  u16* Vtb = (u16*)ws;  ws += 4194304;
  u16* AO = (u16*)ws;   ws += 16777216;

  k_convert<<<2048, 256, 0, stream>>>(x, qw, kw, vw, ow, xb, qwb, kwb, vwb, owb);
  k_gemm_qkv<<<dim3(24, 16), 512, 0, stream>>>(xb, qwb, kwb, vwb, qb, kb, vb,
                                               Qb, Kb, Vtb);
  k_attn<<<dim3(32, 32), 256, 0, stream>>>(Qb, Kb, Vtb, AO);
  k_gemm_o<<<dim3(16, 16), 512, 0, stream>>>(AO, owb, ob, OUT);
}

// Round 3
// 568.697 us; speedup vs baseline: 1.0309x; 1.0111x over previous
//
#include <hip/hip_runtime.h>
#include <hip/hip_bf16.h>
#include <stdint.h>

#define SEQL 2048
#define EMB 4096
#define KVDIM 1024
#define HD 128

typedef __attribute__((ext_vector_type(4))) float f32x4;
typedef __attribute__((ext_vector_type(8))) short bf16x8;
typedef unsigned short u16;
typedef unsigned int u32;

__device__ __forceinline__ u16 f2bf(float f) {
  u32 u = __builtin_bit_cast(u32, f);
  u = (u + 0x7FFFu + ((u >> 16) & 1u)) >> 16;
  return (u16)u;
}

__device__ __forceinline__ void gload_lds16(const void* g, void* l) {
  __builtin_amdgcn_global_load_lds(
      (const __attribute__((address_space(1))) void*)g,
      (__attribute__((address_space(3))) void*)l, 16, 0, 0);
}

#define MFMA16(a, b, c) __builtin_amdgcn_mfma_f32_16x16x32_bf16(a, b, c, 0, 0, 0)
#define SBAR() asm volatile("s_barrier" ::: "memory")
#define LGKM0()                                        \
  do {                                                 \
    asm volatile("s_waitcnt lgkmcnt(0)" ::: "memory"); \
    __builtin_amdgcn_sched_barrier(0);                 \
  } while (0)
#define VM4() asm volatile("s_waitcnt vmcnt(4)" ::: "memory")

// ---------------- fp32 -> bf16 conversion (x + 4 weight matrices) ------------
__global__ __launch_bounds__(256) void k_convert(
    const float* __restrict__ x, const float* __restrict__ qw,
    const float* __restrict__ kw, const float* __restrict__ vw,
    const float* __restrict__ ow, u16* __restrict__ xb, u16* __restrict__ qwb,
    u16* __restrict__ kwb, u16* __restrict__ vwb, u16* __restrict__ owb) {
  const long NCH = 6291456;  // 50331648 / 8
  const long stride = (long)gridDim.x * 256;
  for (long c = (long)blockIdx.x * 256 + threadIdx.x; c < NCH; c += stride) {
    long i = c << 3;
    const float* s;
    u16* d;
    long off;
    if (i < 8388608) {
      s = x; d = xb; off = i;
    } else if (i < 25165824) {
      s = qw; d = qwb; off = i - 8388608;
    } else if (i < 29360128) {
      s = kw; d = kwb; off = i - 25165824;
    } else if (i < 33554432) {
      s = vw; d = vwb; off = i - 29360128;
    } else {
      s = ow; d = owb; off = i - 33554432;
    }
    float4 a = *(const float4*)(s + off);
    float4 b = *(const float4*)(s + off + 4);
    bf16x8 o;
    o[0] = f2bf(a.x); o[1] = f2bf(a.y); o[2] = f2bf(a.z); o[3] = f2bf(a.w);
    o[4] = f2bf(b.x); o[5] = f2bf(b.y); o[6] = f2bf(b.z); o[7] = f2bf(b.w);
    *(bf16x8*)(d + off) = o;
  }
}

// ---- 256x256-tile 8-phase GEMM core (C = A * B^T), K=4096 -------------------
// 512 threads = 8 waves (2M x 4N), per-wave output 128x64.
// LDS: 2 bufs x 64KB; buf: A 256x64 (32KB) @0, B 256x64 @32768.
// Swizzle: granule slot s of row r holds global granule s^(r&7)  (16B granules).
// Schedule (iter i: kt=2i from buf0 in ph1-4, kt+1 from buf1 in ph5-8):
//  ph1: ldA(mh0)+ldB(nh0) | stage buf1.A0<-kt+1 | MFMA q(0,0)
//  ph2: ldB(nh1)           | stage buf1.A1<-kt+1 | MFMA q(0,1)
//  ph3: ldA(mh1)           | stage buf0.B0<-kt+2 | MFMA q(1,0)
//  ph4: --                 | stage buf0.B1<-kt+2 | MFMA q(1,1) | vmcnt(4)
//  ph5-8: same with bufs swapped; stages buf0.A<-kt+2, buf1.B<-kt+3 | vmcnt(4)
// vmcnt(4) at ph4/ph8 == 2 half-tiles (4 loads) in flight; guarantees the
// half-tiles read 1-4 phases later have landed. Region death verified by the
// per-phase end-barriers (B halves die end-ph2, A halves die end-ph3).
__device__ __forceinline__ void gemm256_8ph(const u16* __restrict__ A,
                                            const u16* __restrict__ B,
                                            long aRow0, long bRow0, int lda,
                                            int ldb, char* lds,
                                            f32x4 acc[8][4]) {
  const int t = threadIdx.x, lane = t & 63, w = t >> 6;
  const int wr = w >> 2, wc = w & 3;
  const int r15 = lane & 15, hi = lane >> 4;
  const int rsub = lane >> 3;
  const int gofs = ((lane & 7) ^ rsub) << 3;  // pre-swizzled src granule (elems)
  const int x7 = r15 & 7;
  const int swz0 = (hi ^ x7) << 4;        // kk=0 granule -> byte
  const int swz1 = ((4 + hi) ^ x7) << 4;  // kk=1

  auto stA = [&](int buf, int half, int kt) {
    const long k0 = (long)kt * 64 + gofs;
    char* dst = lds + buf * 65536 + half * 16384 + w * 1024;
    const u16* s = A + (aRow0 + half * 128 + w * 8 + rsub) * (long)lda + k0;
    gload_lds16(s, dst);
    gload_lds16(s + 64 * (long)lda, dst + 8192);
  };
  auto stB = [&](int buf, int half, int kt) {
    const long k0 = (long)kt * 64 + gofs;
    char* dst = lds + buf * 65536 + 32768 + half * 16384 + w * 1024;
    const u16* s = B + (bRow0 + half * 128 + w * 8 + rsub) * (long)ldb + k0;
    gload_lds16(s, dst);
    gload_lds16(s + 64 * (long)ldb, dst + 8192);
  };

  bf16x8 aF[4][2], bF[4][2];
  auto ldA = [&](int cur, int mh) {
    const char* p = lds + cur * 65536;
#pragma unroll
    for (int m = 0; m < 4; ++m) {
      const int r = wr * 128 + mh * 64 + m * 16 + r15;
      aF[m][0] = *(const bf16x8*)(p + r * 128 + swz0);
      aF[m][1] = *(const bf16x8*)(p + r * 128 + swz1);
    }
  };
  auto ldB = [&](int cur, int nh) {
    const char* p = lds + cur * 65536 + 32768;
#pragma unroll
    for (int n = 0; n < 2; ++n) {
      const int r = wc * 64 + (nh * 2 + n) * 16 + r15;
      bF[nh * 2 + n][0] = *(const bf16x8*)(p + r * 128 + swz0);
      bF[nh * 2 + n][1] = *(const bf16x8*)(p + r * 128 + swz1);
    }
  };
  auto MF = [&](int mh, int nh) {
    __builtin_amdgcn_s_setprio(1);
#pragma unroll
    for (int m = 0; m < 4; ++m)
#pragma unroll
      for (int n = 0; n < 2; ++n) {
        const int am = mh * 4 + m, bn = nh * 2 + n;
        acc[am][bn] = MFMA16(aF[m][0], bF[bn][0], acc[am][bn]);
        acc[am][bn] = MFMA16(aF[m][1], bF[bn][1], acc[am][bn]);
      }
    __builtin_amdgcn_s_setprio(0);
  };

  // prologue: tile0 full into buf0, tile1 B-halves into buf1
  stA(0, 0, 0); stA(0, 1, 0); stB(0, 0, 0); stB(0, 1, 0);
  stB(1, 0, 1); stB(1, 1, 1);
  VM4();  // tile0's 8 loads landed (4 newest may fly)
  SBAR();

  for (int i = 0; i < 32; ++i) {
    const int t1 = (2 * i + 1) & 63, t2 = (2 * i + 2) & 63, t3 = (2 * i + 3) & 63;
    // ---- kt = 2i from buf0 ----
    ldA(0, 0); ldB(0, 0); stA(1, 0, t1); SBAR(); LGKM0(); MF(0, 0); SBAR();
    ldB(0, 1);            stA(1, 1, t1); SBAR(); LGKM0(); MF(0, 1); SBAR();
    ldA(0, 1);            stB(0, 0, t2); SBAR(); LGKM0(); MF(1, 0); SBAR();
                          stB(0, 1, t2); SBAR();          MF(1, 1); VM4(); SBAR();
    // ---- kt+1 from buf1 ----
    ldA(1, 0); ldB(1, 0); stA(0, 0, t2); SBAR(); LGKM0(); MF(0, 0); SBAR();
    ldB(1, 1);            stA(0, 1, t2); SBAR(); LGKM0(); MF(0, 1); SBAR();
    ldA(1, 1);            stB(1, 0, t3); SBAR(); LGKM0(); MF(1, 0); SBAR();
                          stB(1, 1, t3); SBAR();          MF(1, 1); VM4(); SBAR();
  }
}

// ---------------- fused QKV projection (256^2 tiles) -------------------------
__global__ __launch_bounds__(512, 2) void k_gemm_qkv(
    const u16* __restrict__ xb, const u16* __restrict__ qwb,
    const u16* __restrict__ kwb, const u16* __restrict__ vwb,
    const float* __restrict__ qb, const float* __restrict__ kb,
    const float* __restrict__ vb, u16* __restrict__ Q, u16* __restrict__ Kc,
    u16* __restrict__ Vt) {
  __shared__ char lds[131072];
  const int nt = blockIdx.x, mt = blockIdx.y;
  const u16* W;
  const float* bias;
  long n0;
  int mode;
  if (nt < 16) {
    W = qwb; bias = qb; n0 = (long)nt * 256; mode = 0;
  } else if (nt < 20) {
    W = kwb; bias = kb; n0 = (long)(nt - 16) * 256; mode = 1;
  } else {
    W = vwb; bias = vb; n0 = (long)(nt - 20) * 256; mode = 2;
  }
  const long m0 = (long)mt * 256;
  f32x4 acc[8][4] = {};
  gemm256_8ph(xb, W, m0, n0, EMB, EMB, lds, acc);
  const int lane = threadIdx.x & 63, w = threadIdx.x >> 6;
  const int wr = w >> 2, wc = w & 3, r15 = lane & 15, hi = lane >> 4;
#pragma unroll
  for (int n = 0; n < 4; ++n) {
    const long col = n0 + wc * 64 + n * 16 + r15;
    const float bv = bias[col];
#pragma unroll
    for (int m = 0; m < 8; ++m) {
#pragma unroll
      for (int j = 0; j < 4; ++j) {
        const long row = m0 + wr * 128 + m * 16 + hi * 4 + j;
        const float v = acc[m][n][j] + bv;
        if (mode == 0)
          Q[row * EMB + col] = f2bf(v);
        else if (mode == 1)
          Kc[row * KVDIM + col] = f2bf(v);
        else
          Vt[col * SEQL + row] = f2bf(v);  // V stored transposed [kv_feat][s]
      }
    }
  }
}

// ---------------- flash attention, base-2 softermax, 64-row q-tiles ---------
__global__ __launch_bounds__(256, 3) void k_attn(const u16* __restrict__ Q,
                                                 const u16* __restrict__ Kc,
                                                 const u16* __restrict__ Vt,
                                                 u16* __restrict__ AO) {
  __shared__ u16 sK[64 * 128];   // [key][d], XOR-swizzled 16B granules
  __shared__ u16 sV[128 * 64];   // [d][key], XOR-swizzled
  __shared__ u16 sP[4][16 * 72]; // per-wave P, pad +8
  const int h = blockIdx.y, kvh = h >> 2;
  const long q0 = (long)blockIdx.x * 64;
  const int t = threadIdx.x, lane = t & 63, w = t >> 6;
  const int r15 = lane & 15, hi = lane >> 4, kof = hi * 8;
  const float scale = 0.08838834764831845f;  // 1/sqrt(128)

  bf16x8 qf[4];
#pragma unroll
  for (int ks = 0; ks < 4; ++ks)
    qf[ks] = *(const bf16x8*)(Q + (q0 + w * 16 + r15) * EMB + h * HD + ks * 32 + kof);

  f32x4 oacc[8] = {};
  float mx[4], sms[4];
#pragma unroll
  for (int i = 0; i < 4; ++i) {
    mx[i] = -1e30f;
    sms[i] = 0.f;
  }

  for (int tk = 0; tk < 32; ++tk) {
    const long k0 = (long)tk * 64;
    __syncthreads();  // prior tile's LDS reads complete
#pragma unroll
    for (int i = 0; i < 4; ++i) {
      const int P = (i * 256 + t) * 16;
      const int row = P >> 8;
      const int cb = (P & 255) ^ ((row & 7) << 4);
      gload_lds16(Kc + (k0 + row) * KVDIM + kvh * HD + (cb >> 1),
                  (char*)sK + (i * 256 + w * 64) * 16);
      const int rowv = P >> 7;
      const int cbv = (P & 127) ^ ((rowv & 7) << 4);
      gload_lds16(Vt + (long)(kvh * HD + rowv) * SEQL + k0 + (cbv >> 1),
                  (char*)sV + (i * 256 + w * 64) * 16);
    }
    __syncthreads();  // staging complete
    f32x4 sacc[4] = {};
#pragma unroll
    for (int ks = 0; ks < 4; ++ks) {
      bf16x8 bF[4];
#pragma unroll
      for (int n = 0; n < 4; ++n) {
        const int row = n * 16 + r15;
        const int off = (row << 8) + (((ks * 32 + kof) << 1) ^ ((row & 7) << 4));
        bF[n] = *(const bf16x8*)((const char*)sK + off);
      }
#pragma unroll
      for (int n = 0; n < 4; ++n)
        sacc[n] = MFMA16(qf[ks], bF[n], sacc[n]);
    }
#pragma unroll
    for (int i = 0; i < 4; ++i) {
      const float pm = fmaxf(fmaxf(sacc[0][i], sacc[1][i]),
                             fmaxf(sacc[2][i], sacc[3][i]));
      if (__any(pm * scale > mx[i] + 8.0f)) {
        float tmax = pm;
#pragma unroll
        for (int msk = 1; msk < 16; msk <<= 1)
          tmax = fmaxf(tmax, __shfl_xor(tmax, msk, 64));
        const float nm = fmaxf(mx[i], tmax * scale);
        const float corr = exp2f(mx[i] - nm);
        mx[i] = nm;
        sms[i] *= corr;
#pragma unroll
        for (int n = 0; n < 8; ++n) oacc[n][i] *= corr;
      }
      float ps = 0.f;
#pragma unroll
      for (int n = 0; n < 4; ++n) {
        const float p = exp2f(sacc[n][i] * scale - mx[i]);
        ps += p;
        sP[w][(hi * 4 + i) * 72 + n * 16 + r15] = f2bf(p);
      }
      sms[i] += ps;
    }
#pragma unroll
    for (int ks = 0; ks < 2; ++ks) {
      const bf16x8 pF = *(const bf16x8*)(&sP[w][r15 * 72 + ks * 32 + kof]);
#pragma unroll
      for (int n = 0; n < 8; ++n) {
        const int row = n * 16 + r15;
        const int off = (row << 7) + (((ks * 32 + kof) << 1) ^ ((row & 7) << 4));
        const bf16x8 vF = *(const bf16x8*)((const char*)sV + off);
        oacc[n] = MFMA16(pF, vF, oacc[n]);
      }
    }
  }
  float inv[4];
#pragma unroll
  for (int i = 0; i < 4; ++i) {
    float s = sms[i];
#pragma unroll
    for (int msk = 1; msk < 16; msk <<= 1) s += __shfl_xor(s, msk, 64);
    inv[i] = 1.f / s;
  }
#pragma unroll
  for (int n = 0; n < 8; ++n)
#pragma unroll
    for (int i = 0; i < 4; ++i)
      AO[(q0 + w * 16 + hi * 4 + i) * EMB + h * HD + n * 16 + r15] =
          f2bf(oacc[n][i] * inv[i]);
}

// ---------------- output projection (256^2 tiles, fp32 out) ------------------
__global__ __launch_bounds__(512, 2) void k_gemm_o(const u16* __restrict__ AO,
                                                   const u16* __restrict__ owb,
                                                   const float* __restrict__ ob,
                                                   float* __restrict__ OUT) {
  __shared__ char lds[131072];
  const long n0 = (long)blockIdx.x * 256, m0 = (long)blockIdx.y * 256;
  f32x4 acc[8][4] = {};
  gemm256_8ph(AO, owb, m0, n0, EMB, EMB, lds, acc);
  const int lane = threadIdx.x & 63, w = threadIdx.x >> 6;
  const int wr = w >> 2, wc = w & 3, r15 = lane & 15, hi = lane >> 4;
#pragma unroll
  for (int n = 0; n < 4; ++n) {
    const long col = n0 + wc * 64 + n * 16 + r15;
    const float bv = ob[col];
#pragma unroll
    for (int m = 0; m < 8; ++m) {
#pragma unroll
      for (int j = 0; j < 4; ++j) {
        const long row = m0 + wr * 128 + m * 16 + hi * 4 + j;
        OUT[row * EMB + col] = acc[m][n][j] + bv;
      }
    }
  }
}

extern "C" void kernel_launch(void* const* d_in, const int* in_sizes, int n_in,
                              void* d_out, int out_size, void* d_ws,
                              size_t ws_size, hipStream_t stream) {
  const float* x = (const float*)d_in[0];
  const float* qw = (const float*)d_in[1];
  const float* qb = (const float*)d_in[2];
  const float* kw = (const float*)d_in[3];
  const float* kb = (const float*)d_in[4];
  const float* vw = (const float*)d_in[5];
  const float* vb = (const float*)d_in[6];
  const float* ow = (const float*)d_in[7];
  const float* ob = (const float*)d_in[8];
  float* OUT = (float*)d_out;

  char* ws = (char*)d_ws;
  u16* xb = (u16*)ws;   ws += 16777216;
  u16* qwb = (u16*)ws;  ws += 33554432;
  u16* kwb = (u16*)ws;  ws += 8388608;
  u16* vwb = (u16*)ws;  ws += 8388608;
  u16* owb = (u16*)ws;  ws += 33554432;
  u16* Qb = (u16*)ws;   ws += 16777216;
  u16* Kb = (u16*)ws;   ws += 4194304;
  u16* Vtb = (u16*)ws;  ws += 4194304;
  u16* AO = (u16*)ws;   ws += 16777216;

  k_convert<<<2048, 256, 0, stream>>>(x, qw, kw, vw, ow, xb, qwb, kwb, vwb, owb);
  k_gemm_qkv<<<dim3(24, 8), 512, 0, stream>>>(xb, qwb, kwb, vwb, qb, kb, vb,
                                              Qb, Kb, Vtb);
  k_attn<<<dim3(32, 32), 256, 0, stream>>>(Qb, Kb, Vtb, AO);
  k_gemm_o<<<dim3(16, 8), 512, 0, stream>>>(AO, owb, ob, OUT);
}